// Round 3
// baseline (645.385 us; speedup 1.0000x reference)
//
#include <hip/hip_runtime.h>

// Shapes fixed by the reference setup: B=32, N=64, L=128, D=256.
#define BB 32
#define NN 64
#define LL 128
#define DD 256
#define NBTOT (BB * NN)     // 2048
#define MAX_LEN (NN * LL)   // 8192
#define D4 (DD / 4)         // 64 float4 per row
#define NSLOT 8             // ws partial slots for enc_hidden reduction

typedef float f32x4 __attribute__((ext_vector_type(4)));

// ---------------------------------------------------------------------------
// Kernel 1: per-batch inclusive prefix sum of lengths (wave64 scan);
// writes cum[b][n], inv_total[b], lengths_out[b]; zeroes ws_part.
// ---------------------------------------------------------------------------
__global__ __launch_bounds__(64) void prefix_kernel(
    const int* __restrict__ lengths,
    int* __restrict__ cum,          // ws: [B][N]
    float* __restrict__ inv_total,  // ws: [B]
    float* __restrict__ lengths_out,// out3: [B]
    float* __restrict__ ws_part)    // ws: [B][D][NSLOT] (zero-init here)
{
    const int b = blockIdx.x;
    const int lane = threadIdx.x;

    int v = lengths[b * NN + lane];
    #pragma unroll
    for (int s = 1; s < 64; s <<= 1) {
        int o = __shfl_up(v, s, 64);
        if (lane >= s) v += o;
    }
    cum[b * NN + lane] = v;

    const int total = __shfl(v, 63, 64);
    if (lane == 0) {
        lengths_out[b] = (float)total;
        inv_total[b] = (total > 0) ? (1.0f / (float)total) : 0.0f;
    }

    // zero ws_part: 32*256*8 = 65536 floats, 2048 threads -> 32 each, coalesced
    const int tg = b * 64 + lane;
    #pragma unroll
    for (int k = 0; k < (BB * DD * NSLOT) / (BB * 64); ++k)
        ws_part[k * (BB * 64) + tg] = 0.0f;
}

// ---------------------------------------------------------------------------
// Kernel 2: OUTPUT-ROW-MAJOR gather + inline zero-fill + LDS mean partials.
//
// Output row r = t*32 + b. Block owns 256 consecutive r; each wave streams
// 64 consecutive rows -> every wave iteration stores 1 KB contiguous, the
// wave covers 64 KB contiguous, and the grid covers mb_out IN ORDER: one
// fully linear write stream (vs the previous b-major layout's 1 KB stores
// at 32 KB stride, whose L2 evictions reach DRAM sub-KB-scattered at
// ~4.7 TB/s). Reads stay irreducibly 1 KB-scattered (row permutation).
// Valid/zero choice is wave-uniform per row (from a ballot mask).
// enc_hidden: LDS s_acc[32][256] via ds-atomics (conflict-free layout,
// component-permuted), flushed to 8-slot global partials per block.
// ---------------------------------------------------------------------------
__global__ __launch_bounds__(256) void gather_kernel(
    const float* __restrict__ src,       // [L][NB]
    const f32x4* __restrict__ mb,        // [L][NB][D] as float4
    const int* __restrict__ recover,     // [NB]
    const int* __restrict__ cum,         // [B][N]
    float* __restrict__ src_out,         // [MAX_LEN][B] (= linear in r)
    f32x4* __restrict__ mb_out,          // [MAX_LEN][B][D] as float4
    float* __restrict__ ws_part)         // [B][D][NSLOT]
{
    __shared__ int   s_cum[BB][NN + 1];  // +1 pad: bank-spread the search
    __shared__ float s_acc[BB * DD];     // [b][perm-chan]
    __shared__ int   s_any;

    const int tid  = threadIdx.x;
    const int wave = tid >> 6;
    const int lane = tid & 63;
    const int r0   = blockIdx.x * 256;   // first output row of this block
    const int t0   = r0 >> 5;            // min t in block (= blockIdx.x*8)

    for (int k = tid; k < BB * NN; k += 256)
        s_cum[k >> 6][k & 63] = cum[k];
    for (int k = tid; k < BB * DD; k += 256)
        s_acc[k] = 0.0f;
    if (tid == 0) s_any = 0;
    __syncthreads();

    // ---- per-thread params for row r = r0 + tid ----
    const int r = r0 + tid;
    const int b = tid & 31;              // = r & 31
    const int t = r >> 5;
    const int total = s_cum[b][NN - 1];
    const bool valid = (t < total);

    // n = number of cum[b] entries <= t
    int n = 0;
    #pragma unroll
    for (int s = 32; s >= 1; s >>= 1) {
        const int cand = n + s;
        if (cand <= NN && s_cum[b][cand - 1] <= t) n = cand;
    }
    const int l = t - ((n > 0) ? s_cum[b][n - 1] : 0);
    const int rowidx = l * NBTOT + b * NN + n;   // f32x4-row index into mb

    if (valid) s_any = 1;                // benign race, read after barrier

    // src_out: linear store (src_out[t][b] == src_out[r])
    float sv = 1.0f;
    if (valid) sv = src[(size_t)l * NBTOT + recover[b * NN + n]];
    src_out[r] = sv;

    const unsigned long long vmask = __ballot(valid); // bit j = row rw+j valid

    // ---- streaming: wave's 64 consecutive output rows ----
    const int rw = r0 + wave * 64;
    f32x4* const outp = mb_out + (size_t)rw * D4 + lane;
    const f32x4 z = {0.f, 0.f, 0.f, 0.f};

    for (int jb = 0; jb < 8; ++jb) {
        int   rj[8];
        f32x4 v[8];
        #pragma unroll
        for (int k = 0; k < 8; ++k)
            rj[k] = __shfl(rowidx, jb * 8 + k, 64);  // wave-uniform
        #pragma unroll
        for (int k = 0; k < 8; ++k) {
            const int j = jb * 8 + k;
            if ((vmask >> j) & 1)                    // uniform branch
                v[k] = __builtin_nontemporal_load(&mb[(size_t)rj[k] * D4 + lane]);
            else
                v[k] = z;
        }
        #pragma unroll
        for (int k = 0; k < 8; ++k) {
            const int j = jb * 8 + k;
            __builtin_nontemporal_store(v[k], outp + (size_t)j * D4);
            if ((vmask >> j) & 1) {                  // uniform branch
                const int bj = (rw + j) & 31;        // uniform per j
                // perm layout: component c of lane L -> index c*64+L
                // (addresses mod 32 = lane&31 -> 2 lanes/bank, conflict-free)
                float* const ap = &s_acc[bj * DD];
                atomicAdd(ap + 0 * 64 + lane, v[k].x);
                atomicAdd(ap + 1 * 64 + lane, v[k].y);
                atomicAdd(ap + 2 * 64 + lane, v[k].z);
                atomicAdd(ap + 3 * 64 + lane, v[k].w);
            }
        }
    }

    __syncthreads();
    if (s_any) {
        const int slot = blockIdx.x & (NSLOT - 1);
        #pragma unroll 4
        for (int b2 = 0; b2 < BB; ++b2) {
            if (s_cum[b2][NN - 1] > t0) {            // this b contributes here
                const float pv = s_acc[b2 * DD + tid];
                atomicAdd(&ws_part[(b2 * DD + tid) * NSLOT + slot], pv);
            }
        }
    }
}

// ---------------------------------------------------------------------------
// Kernel 3: enc_hidden[b][c] = inv_total[b] * sum_slots ws_part[b][perm(c)][s]
// ---------------------------------------------------------------------------
__global__ __launch_bounds__(256) void finalize_kernel(
    const float* __restrict__ ws_part,
    const float* __restrict__ inv_total,
    float* __restrict__ enc_hidden)      // [B][D]
{
    const int b = blockIdx.x;
    const int c = threadIdx.x;                   // real channel
    const int p = (c & 3) * 64 + (c >> 2);       // permuted index used by s_acc
    float s = 0.0f;
    #pragma unroll
    for (int k = 0; k < NSLOT; ++k)
        s += ws_part[(b * DD + p) * NSLOT + k];
    enc_hidden[b * DD + c] = s * inv_total[b];
}

// ---------------------------------------------------------------------------
extern "C" void kernel_launch(void* const* d_in, const int* in_sizes, int n_in,
                              void* d_out, int out_size, void* d_ws, size_t ws_size,
                              hipStream_t stream) {
    const float* src     = (const float*)d_in[0];   // [L, NB, 1]
    const float* mb      = (const float*)d_in[1];   // [L, NB, D]
    const int*   lengths = (const int*)d_in[2];     // [NB]
    const int*   recover = (const int*)d_in[3];     // [NB]

    float* out = (float*)d_out;
    float* src_out     = out;                                   // 262144
    float* mb_out      = out + (size_t)MAX_LEN * BB;            // 67108864
    float* enc_hidden  = mb_out + (size_t)MAX_LEN * BB * DD;    // 8192
    float* lengths_out = enc_hidden + (size_t)BB * DD;          // 32

    int*   cum       = (int*)d_ws;                              // 8 KB
    float* inv_total = (float*)((char*)d_ws + NBTOT * sizeof(int));
    float* ws_part   = (float*)((char*)d_ws + 16384);           // 256 KB

    prefix_kernel<<<BB, 64, 0, stream>>>(lengths, cum, inv_total,
                                         lengths_out, ws_part);

    gather_kernel<<<(MAX_LEN * BB) / 256, 256, 0, stream>>>(
        src, (const f32x4*)mb, recover, cum,
        src_out, (f32x4*)mb_out, ws_part);

    finalize_kernel<<<BB, 256, 0, stream>>>(ws_part, inv_total, enc_hidden);
}